// Round 7
// baseline (11567.080 us; speedup 1.0000x reference)
//
#include <hip/hip_runtime.h>
#include <math.h>

#define TT 1024
#define BB 256
#define DD 16
#define HH 128
#define CC 64

__device__ __forceinline__ float rcp_f(float x) { return __builtin_amdgcn_rcpf(x); }
__device__ __forceinline__ float spf(float x) {
  float e = __expf(-fabsf(x));
  return fmaxf(x, 0.0f) + __logf(1.0f + e);
}
__device__ __forceinline__ float sigf(float x) {
  return rcp_f(1.0f + __expf(-x));
}
__device__ __forceinline__ float tanh_f(float x) {
  float e = __expf(-2.0f * fabsf(x));
  float t = (1.0f - e) * rcp_f(1.0f + e);
  return x < 0.0f ? -t : t;
}

template<int NQ>
__device__ __forceinline__ float dotnq(const float4* w, const float* v) {
  float acc[4] = {0.f, 0.f, 0.f, 0.f};
  #pragma unroll
  for (int q = 0; q < NQ; ++q) {
    float4 vv = *(const float4*)(v + 4*q);
    acc[q & 3] = fmaf(w[q].x, vv.x, fmaf(w[q].y, vv.y,
                 fmaf(w[q].z, vv.z, fmaf(w[q].w, vv.w, acc[q & 3]))));
  }
  return (acc[0] + acc[1]) + (acc[2] + acc[3]);
}

// ---------------------------------------------------------------------------
// Encoder: backward GRU, fused ctx projection. One WG (768 thr) per batch elem.
// Thread PAIR (2k,2k+1) owns GRU row k: each holds HALF the Whh/Wih row
// (16+2 float4 = 72 VGPR) so the working set fits the toolchain's hard
// 128-VGPR cap (rounds 2/5/6: cap immovable via launch_bounds/attributes;
// full-row layout spilled and ran 4x slow). Halves combine via shfl_xor(1).
// ---------------------------------------------------------------------------
__global__ __launch_bounds__(768) void enc_kernel(
    const float* __restrict__ xs, const float* __restrict__ Wih,
    const float* __restrict__ Whh, const float* __restrict__ bih,
    const float* __restrict__ bhh, const float* __restrict__ encW,
    const float* __restrict__ encB, float* __restrict__ ctx)
{
  const int b = blockIdx.x;
  const int j = threadIdx.x;
  const int row = j >> 1;          // 0..383
  const int half = j & 1;
  __shared__ __align__(16) float hs[HH];
  __shared__ __align__(16) float xsh[DD];
  __shared__ __align__(16) float gsum[2*HH];
  __shared__ __align__(16) float gin[HH];
  __shared__ __align__(16) float ghn[HH];
  __shared__ float4 ew[32][CC];    // ew[k4][c] = encW[c][4k4..4k4+3]

  float4 wh[16];
  #pragma unroll
  for (int q = 0; q < 16; ++q) wh[q] = *(const float4*)(Whh + row*HH + half*64 + 4*q);
  float4 wi[2];
  #pragma unroll
  for (int q = 0; q < 2; ++q) wi[q] = *(const float4*)(Wih + row*DD + half*8 + 4*q);
  const float bi = bih[row];
  const float bh = bhh[row];
  const float eb = (j < 2*CC) ? encB[j >> 1] : 0.0f;

  if (j < HH) hs[j] = 0.0f;
  for (int idx = j; idx < 32*CC; idx += 768) {
    int k4 = idx >> 6, c = idx & 63;
    ew[k4][c] = *(const float4*)(encW + c*HH + 4*k4);
  }
  if (j >= 752) xsh[j - 752] = xs[((size_t)(TT-1)*BB + b)*DD + (j - 752)];
  __syncthreads();

  for (int t = TT-1; t >= 0; --t) {
    float xnext = 0.0f;
    if (j >= 752) {
      int tm = (t > 0) ? (t - 1) : 0;
      xnext = xs[((size_t)tm*BB + b)*DD + (j - 752)];
    }
    float gi = dotnq<2>(wi, xsh + half*8);
    float gh = dotnq<16>(wh, hs + half*64);
    float gi_t = gi + __shfl_xor(gi, 1);
    float gh_t = gh + __shfl_xor(gh, 1);
    if (!half) {
      if (row < 2*HH) gsum[row] = gi_t + gh_t + bi + bh;
      else { gin[row - 2*HH] = gi_t + bi; ghn[row - 2*HH] = gh_t + bh; }
    }
    __syncthreads();   // A
    if (j < HH) {
      float rg = sigf(gsum[j]);
      float zg = sigf(gsum[HH + j]);
      float ng = tanh_f(gin[j] + rg * ghn[j]);
      hs[j] = (1.0f - zg) * ng + zg * hs[j];
    }
    if (j >= 752) xsh[j - 752] = xnext;
    __syncthreads();   // B
    if (j < 2*CC) {    // projection: pair per column c = j>>1
      int c = j >> 1;
      float a0 = 0.f, a1 = 0.f, a2 = 0.f, a3 = 0.f;
      #pragma unroll
      for (int qq = 0; qq < 16; ++qq) {
        int q = half*16 + qq;
        float4 hv = *(const float4*)(hs + 4*q);
        float4 wv = ew[q][c];
        float t0 = fmaf(wv.x, hv.x, fmaf(wv.y, hv.y, 0.f));
        float t1 = fmaf(wv.z, hv.z, fmaf(wv.w, hv.w, 0.f));
        if (qq & 1) { a2 += t0; a3 += t1; } else { a0 += t0; a1 += t1; }
      }
      float p = (a0 + a1) + (a2 + a3);
      p += __shfl_xor(p, 1);
      if (!half) ctx[((size_t)t*BB + b)*CC + c] = eb + p;
    }
  }
}

// ---------------------------------------------------------------------------
// Fused SDE scan. One WG (1024 thr, 16 waves) per batch elem. Thread pairs
// own half-rows (max 18 float4 = 72 VGPR weights -> fits 128-VGPR cap, no
// spill). 3 barriers/step: P0 {fL1+g, hL1, hd-head(prev)}, P1 {fL2, hL2},
// P2 {fd-head+z-update, hL3, ctx-stage}. hd-head pipelined one step behind.
// Roles: w0-3 fW1+g | w4-7 fW2 (w5 fd-head, w6 hd-head, w7 ctx) | w8-11
// hW1+hW2 | w12-15 hW3.
// ---------------------------------------------------------------------------
__global__ __launch_bounds__(1024) void sde_kernel(
    const float* __restrict__ xs, const float* __restrict__ tsv,
    const float* __restrict__ noise,
    const float* __restrict__ fW1, const float* __restrict__ fb1,
    const float* __restrict__ fW2, const float* __restrict__ fb2,
    const float* __restrict__ fW3, const float* __restrict__ fb3,
    const float* __restrict__ hW1, const float* __restrict__ hb1,
    const float* __restrict__ hW2, const float* __restrict__ hb2,
    const float* __restrict__ hW3, const float* __restrict__ hb3,
    const float* __restrict__ hW4, const float* __restrict__ hb4,
    const float* __restrict__ gW1, const float* __restrict__ gb1,
    const float* __restrict__ gW2, const float* __restrict__ gb2,
    const float* __restrict__ ctx, float* __restrict__ out)
{
  const int b = blockIdx.x;
  const int j = threadIdx.x;
  const int wid = j >> 6;
  const int lane = j & 63;
  const int dq_d = lane >> 2;
  const int dq_q = lane & 3;

  __shared__ __align__(16) float zv[DD];
  __shared__ __align__(16) float ctxb[2][CC];
  __shared__ __align__(16) float x1[HH];
  __shared__ __align__(16) float x2s[HH];
  __shared__ __align__(16) float hx1[HH];
  __shared__ __align__(16) float hx2[HH];
  __shared__ __align__(16) float hx3[HH];
  __shared__ float w3c[HH][17];    // fW3 col-major, padded
  __shared__ float w4c[HH][17];    // hW4 col-major, padded
  __shared__ float gdpre[DD];
  __shared__ float2 fdgd[DD];

  float4 wM[16], wX[6];
  #pragma unroll
  for (int q = 0; q < 16; ++q) wM[q] = make_float4(0.f,0.f,0.f,0.f);
  #pragma unroll
  for (int q = 0; q < 6; ++q)  wX[q] = make_float4(0.f,0.f,0.f,0.f);
  float bA = 0.f, bB = 0.f;

  if (j < 256) {                       // fL1 half-row + g slice
    int row = j >> 1, hf = j & 1;
    #pragma unroll
    for (int q = 0; q < 10; ++q) wM[q] = *(const float4*)(fW1 + row*80 + hf*40 + 4*q);
    bA = fb1[row];
    int d = j >> 4, h0 = (j & 15) * 8;
    #pragma unroll
    for (int m = 0; m < 2; ++m) {
      wX[m]     = *(const float4*)(gW1 + d*HH + h0 + 4*m);
      wX[2 + m] = *(const float4*)(gb1 + d*HH + h0 + 4*m);
      wX[4 + m] = *(const float4*)(gW2 + d*HH + h0 + 4*m);
    }
  } else if (j < 512) {                // fL2 half-row
    int row = (j - 256) >> 1, hf = j & 1;
    #pragma unroll
    for (int q = 0; q < 16; ++q) wM[q] = *(const float4*)(fW2 + row*HH + hf*64 + 4*q);
    bA = fb2[row];
  } else if (j < 768) {                // hL1 + hL2 half-rows
    int row = (j - 512) >> 1, hf = j & 1;
    #pragma unroll
    for (int q = 0; q < 2; ++q)  wX[q] = *(const float4*)(hW1 + row*DD + hf*8 + 4*q);
    #pragma unroll
    for (int q = 0; q < 16; ++q) wM[q] = *(const float4*)(hW2 + row*HH + hf*64 + 4*q);
    bA = hb1[row]; bB = hb2[row];
  } else {                             // hL3 half-row
    int row = (j - 768) >> 1, hf = j & 1;
    #pragma unroll
    for (int q = 0; q < 16; ++q) wM[q] = *(const float4*)(hW3 + row*HH + hf*64 + 4*q);
    bA = hb3[row];
  }

  float fb3d = 0.f, gb2d = 0.f, hb4d = 0.f;
  if (wid == 5) { fb3d = fb3[dq_d]; gb2d = gb2[dq_d]; }
  if (wid == 6) { hb4d = hb4[dq_d]; }

  // LDS fills
  if (j < HH) {
    #pragma unroll
    for (int d2 = 0; d2 < DD; ++d2) w3c[j][d2] = fW3[d2*HH + j];
  } else if (j < 2*HH) {
    int r = j - HH;
    #pragma unroll
    for (int d2 = 0; d2 < DD; ++d2) w4c[r][d2] = hW4[d2*HH + r];
  }
  if (j < DD) zv[j] = xs[(size_t)b*DD + j];
  if (wid == 7) ctxb[1][lane] = ctx[((size_t)1*BB + b)*CC + lane];

  const float dtc = tsv[1] - tsv[0];
  const float sdt = sqrtf(dtc);
  float nreg = 0.0f;
  if (wid == 5 && dq_q == 0) nreg = noise[(size_t)b*DD + dq_d];
  float lqp = 0.0f;
  __syncthreads();

  for (int i = 0; i < TT-1; ++i) {
    const int cur = (i + 1) & 1;
    const int nxt = i & 1;
    // ---------- P0: fL1 -> x1, g -> gdpre, hL1 -> hx1, hd-head(i-1) ----------
    float nnext = 0.0f, creg = 0.0f;
    if (wid == 5 && dq_q == 0 && (i + 1) < TT-1)
      nnext = noise[((size_t)(i+1)*BB + b)*DD + dq_d];
    if (wid == 7) {
      int t2 = (i + 2 <= TT-1) ? (i + 2) : (TT-1);
      creg = ctx[((size_t)t2*BB + b)*CC + lane];
    }
    if (j < 256) {
      int hf = j & 1;
      float a;
      if (!hf) a = dotnq<4>(wM, zv) + dotnq<6>(wM + 4, ctxb[cur]);
      else     a = dotnq<10>(wM, ctxb[cur] + 24);
      a += __shfl_xor(a, 1);
      if (!hf) x1[j >> 1] = spf(a + bA);
      // g slice
      int d = j >> 4;
      float zd = zv[d];
      float ps = 0.f;
      #pragma unroll
      for (int m = 0; m < 2; ++m) {
        float4 w1v = wX[m], b1v = wX[2 + m], w2v = wX[4 + m];
        ps += spf(fmaf(zd, w1v.x, b1v.x)) * w2v.x;
        ps += spf(fmaf(zd, w1v.y, b1v.y)) * w2v.y;
        ps += spf(fmaf(zd, w1v.z, b1v.z)) * w2v.z;
        ps += spf(fmaf(zd, w1v.w, b1v.w)) * w2v.w;
      }
      ps += __shfl_xor(ps, 1);
      ps += __shfl_xor(ps, 2);
      ps += __shfl_xor(ps, 4);
      ps += __shfl_xor(ps, 8);
      if ((j & 15) == 0) gdpre[d] = ps;
    } else if (j >= 512 && j < 768) {
      int hf = j & 1;
      float a = dotnq<2>(wX, zv + hf*8);
      a += __shfl_xor(a, 1);
      if (!hf) hx1[(j - 512) >> 1] = spf(a + bA);
    } else if (wid == 6 && i > 0) {     // hd head for step i-1
      float ha0 = 0.f, ha1 = 0.f;
      #pragma unroll
      for (int rr = 0; rr < 32; ++rr) {
        int ri = 4*rr + dq_q;
        if (rr & 1) ha1 = fmaf(w4c[ri][dq_d], hx3[ri], ha1);
        else        ha0 = fmaf(w4c[ri][dq_d], hx3[ri], ha0);
      }
      float hacc = ha0 + ha1;
      hacc += __shfl_xor(hacc, 1);
      hacc += __shfl_xor(hacc, 2);
      if (dq_q == 0) {
        float hd = hacc + hb4d;
        float2 fg = fdgd[dq_d];
        float uu = (fg.x - hd) / (fg.y + 1e-7f);
        lqp = fmaf(0.5f * uu * uu, dtc, lqp);
      }
    }
    __syncthreads();
    // ---------- P1: fL2 -> x2s, hL2 -> hx2 ----------
    if (j >= 256 && j < 512) {
      int hf = j & 1, row = (j - 256) >> 1;
      float p = dotnq<16>(wM, x1 + hf*64);
      p += __shfl_xor(p, 1);
      if (!hf) x2s[row] = spf(p + bA);
    } else if (j >= 512 && j < 768) {
      int hf = j & 1, row = (j - 512) >> 1;
      float p = dotnq<16>(wM, hx1 + hf*64);
      p += __shfl_xor(p, 1);
      if (!hf) hx2[row] = spf(p + bB);
    }
    __syncthreads();
    // ---------- P2: fd-head + z-update (w5), hL3 -> hx3, ctx stage (w7) -----
    if (wid == 5) {
      float fa0 = 0.f, fa1 = 0.f;
      #pragma unroll
      for (int rr = 0; rr < 32; ++rr) {
        int ri = 4*rr + dq_q;
        if (rr & 1) fa1 = fmaf(w3c[ri][dq_d], x2s[ri], fa1);
        else        fa0 = fmaf(w3c[ri][dq_d], x2s[ri], fa0);
      }
      float facc = fa0 + fa1;
      facc += __shfl_xor(facc, 1);
      facc += __shfl_xor(facc, 2);
      if (dq_q == 0) {
        float fd = facc + fb3d;
        float gd = spf(gdpre[dq_d] + gb2d);
        float zpre = zv[dq_d];
        float znew = fmaf(fd, dtc, fmaf(gd, sdt * nreg, zpre));
        zv[dq_d] = znew;
        fdgd[dq_d] = make_float2(fd, gd);
        if (dq_d >= 8) {
          out[2 + ((size_t)(i+1)*BB + b)*8 + (dq_d - 8)] = znew;
          if (i == 0) out[2 + (size_t)b*8 + (dq_d - 8)] = zpre;
        }
      }
    } else if (j >= 768) {
      int hf = j & 1, row = (j - 768) >> 1;
      float p = dotnq<16>(wM, hx2 + hf*64);
      p += __shfl_xor(p, 1);
      if (!hf) hx3[row] = spf(p + bA);
    } else if (wid == 7) {
      ctxb[nxt][lane] = creg;
    }
    nreg = nnext;
    __syncthreads();
  }
  // final hd head for step TT-2 + logqp reduce
  if (wid == 6) {
    float ha0 = 0.f, ha1 = 0.f;
    #pragma unroll
    for (int rr = 0; rr < 32; ++rr) {
      int ri = 4*rr + dq_q;
      if (rr & 1) ha1 = fmaf(w4c[ri][dq_d], hx3[ri], ha1);
      else        ha0 = fmaf(w4c[ri][dq_d], hx3[ri], ha0);
    }
    float hacc = ha0 + ha1;
    hacc += __shfl_xor(hacc, 1);
    hacc += __shfl_xor(hacc, 2);
    if (dq_q == 0) {
      float hd = hacc + hb4d;
      float2 fg = fdgd[dq_d];
      float uu = (fg.x - hd) / (fg.y + 1e-7f);
      lqp = fmaf(0.5f * uu * uu, dtc, lqp);
    }
    lqp += __shfl_xor(lqp, 4);
    lqp += __shfl_xor(lqp, 8);
    lqp += __shfl_xor(lqp, 16);
    lqp += __shfl_xor(lqp, 32);
    if (lane == 0) atomicAdd(out + 1, lqp * (1.0f / 256.0f));
  }
}

// ---------------------------------------------------------------------------
// log_pxs reduction: sum over (t,b,o) of log_prob, / B. One block per t.
// ---------------------------------------------------------------------------
__global__ __launch_bounds__(256) void lp_kernel(const float* __restrict__ xs,
                                                 float* __restrict__ out)
{
  const int t = blockIdx.x;
  const int b = threadIdx.x;
  const float cst = 3.6862316527834183f;  // -log(0.01) - 0.5*log(2*pi)
  const float* xrow = xs + ((size_t)t*BB + b)*DD + 8;
  const float* zrow = out + 2 + ((size_t)t*BB + b)*8;
  float acc = 0.f;
  #pragma unroll
  for (int o = 0; o < 8; ++o) {
    float dd = (xrow[o] - zrow[o]) * 100.0f;
    acc += cst - 0.5f * dd * dd;
  }
  #pragma unroll
  for (int m = 1; m < 64; m <<= 1) acc += __shfl_xor(acc, m);
  __shared__ float wpart[4];
  int w = threadIdx.x >> 6;
  if ((threadIdx.x & 63) == 0) wpart[w] = acc;
  __syncthreads();
  if (threadIdx.x == 0)
    atomicAdd(out, (wpart[0] + wpart[1] + wpart[2] + wpart[3]) * (1.0f / 256.0f));
}

extern "C" void kernel_launch(void* const* d_in, const int* in_sizes, int n_in,
                              void* d_out, int out_size, void* d_ws, size_t ws_size,
                              hipStream_t stream) {
  const float* xs    = (const float*)d_in[0];
  const float* tsv   = (const float*)d_in[1];
  const float* noise = (const float*)d_in[2];
  const float* Wih   = (const float*)d_in[3];
  const float* Whh   = (const float*)d_in[4];
  const float* bih   = (const float*)d_in[5];
  const float* bhh   = (const float*)d_in[6];
  const float* encW  = (const float*)d_in[7];
  const float* encB  = (const float*)d_in[8];
  const float* fW1   = (const float*)d_in[9];
  const float* fb1   = (const float*)d_in[10];
  const float* fW2   = (const float*)d_in[11];
  const float* fb2   = (const float*)d_in[12];
  const float* fW3   = (const float*)d_in[13];
  const float* fb3   = (const float*)d_in[14];
  const float* hW1   = (const float*)d_in[15];
  const float* hb1   = (const float*)d_in[16];
  const float* hW2   = (const float*)d_in[17];
  const float* hb2   = (const float*)d_in[18];
  const float* hW3   = (const float*)d_in[19];
  const float* hb3   = (const float*)d_in[20];
  const float* hW4   = (const float*)d_in[21];
  const float* hb4   = (const float*)d_in[22];
  const float* gW1   = (const float*)d_in[23];
  const float* gb1   = (const float*)d_in[24];
  const float* gW2   = (const float*)d_in[25];
  const float* gb2   = (const float*)d_in[26];
  float* out = (float*)d_out;
  float* ctx = (float*)d_ws;   // T*B*C floats = 64 MiB

  hipMemsetAsync(d_out, 0, 2 * sizeof(float), stream);
  enc_kernel<<<BB, 768, 0, stream>>>(xs, Wih, Whh, bih, bhh, encW, encB, ctx);
  sde_kernel<<<BB, 1024, 0, stream>>>(xs, tsv, noise,
                                      fW1, fb1, fW2, fb2, fW3, fb3,
                                      hW1, hb1, hW2, hb2, hW3, hb3, hW4, hb4,
                                      gW1, gb1, gW2, gb2, ctx, out);
  lp_kernel<<<TT, BB, 0, stream>>>(xs, out);
}

// Round 11
// 4288.057 us; speedup vs baseline: 2.6975x; 2.6975x over previous
//
#include <hip/hip_runtime.h>
#include <math.h>

#define TT 1024
#define BB 256
#define DD 16
#define HH 128
#define CC 64

__device__ __forceinline__ float rcp_f(float x) { return __builtin_amdgcn_rcpf(x); }
__device__ __forceinline__ float spf(float x) {
  float e = __expf(-fabsf(x));
  return fmaxf(x, 0.0f) + __logf(1.0f + e);
}
__device__ __forceinline__ float sigf(float x) {
  return rcp_f(1.0f + __expf(-x));
}
__device__ __forceinline__ float tanh_f(float x) {
  float e = __expf(-2.0f * fabsf(x));
  float t = (1.0f - e) * rcp_f(1.0f + e);
  return x < 0.0f ? -t : t;
}
__device__ __forceinline__ unsigned bf16pack(float a, float b) {
  unsigned ua = __float_as_uint(a);
  ua = (ua + 0x7FFFu + ((ua >> 16) & 1u)) >> 16;
  unsigned ub = __float_as_uint(b);
  ub = ((ub + 0x7FFFu + ((ub >> 16) & 1u)) >> 16) << 16;
  return ua | ub;
}

template<int NQ>
__device__ __forceinline__ float dotnq(const float4* w, const float* v) {
  float acc[4] = {0.f, 0.f, 0.f, 0.f};
  #pragma unroll
  for (int q = 0; q < NQ; ++q) {
    float4 vv = *(const float4*)(v + 4*q);
    acc[q & 3] = fmaf(w[q].x, vv.x, fmaf(w[q].y, vv.y,
                 fmaf(w[q].z, vv.z, fmaf(w[q].w, vv.w, acc[q & 3]))));
  }
  return (acc[0] + acc[1]) + (acc[2] + acc[3]);
}

// ---------------------------------------------------------------------------
// Encoder: backward GRU + fused ctx projection. 384 thr/WG, thread j owns full
// GRU row j (Whh row = 32 f4 regs; ~152 VGPR < ~170 cap=65536/384).
// ZERO in-loop global ops: xs prestaged to LDS (64KB), Wih transposed in LDS,
// ctx stores batched 8 steps in LDS, flushed by column-owner threads (each
// reads only its own writes -> race-free) -> barriers drain nothing.
// ---------------------------------------------------------------------------
__global__ __launch_bounds__(384) void enc_kernel(
    const float* __restrict__ xs, const float* __restrict__ Wih,
    const float* __restrict__ Whh, const float* __restrict__ bih,
    const float* __restrict__ bhh, const float* __restrict__ encW,
    const float* __restrict__ encB, float* __restrict__ ctx)
{
  const int b = blockIdx.x;
  const int j = threadIdx.x;
  __shared__ __align__(16) float hs[HH];
  __shared__ float gsum[2*HH];
  __shared__ float gin[HH];
  __shared__ float ghn[HH];
  __shared__ __align__(16) float4 ew[32][CC];   // encW[c][4k..] -> ew[k4][c]
  __shared__ float wiT[16][384];                 // Wih transposed
  __shared__ __align__(16) float xsL[TT][DD];    // xs[:,b,:] 64KB
  __shared__ float stg[8][CC];                   // ctx store stage

  float4 wh[32];
  #pragma unroll
  for (int q = 0; q < 32; ++q) wh[q] = *(const float4*)(Whh + j*HH + 4*q);
  const float bi = bih[j];
  const float bh = bhh[j];
  const float eb = (j < 2*CC) ? encB[j >> 1] : 0.0f;

  for (int e = j; e < 16*384; e += 384) {
    int k = e / 384, r = e % 384;
    wiT[k][r] = Wih[r*DD + k];
  }
  for (int v = j; v < TT*4; v += 384) {   // 4096 float4s
    int t = v >> 2, d4 = v & 3;
    *(float4*)(&xsL[t][d4*4]) = *(const float4*)(xs + (size_t)t*BB*DD + b*DD + d4*4);
  }
  for (int idx = j; idx < 32*CC; idx += 384) {
    int k4 = idx >> 6, c = idx & 63;
    ew[k4][c] = *(const float4*)(encW + c*HH + 4*k4);
  }
  if (j < HH) hs[j] = 0.0f;
  __syncthreads();

  for (int t = TT-1; t >= 0; --t) {
    // C1: gi (LDS Wih^T x LDS xs) + gh (reg row . hs)
    float gi = 0.f;
    #pragma unroll
    for (int k = 0; k < 16; ++k) gi = fmaf(wiT[k][j], xsL[t][k], gi);
    float gh = dotnq<32>(wh, hs);
    if (j < 2*HH) gsum[j] = gi + gh + bi + bh;
    else { gin[j - 2*HH] = gi + bi; ghn[j - 2*HH] = gh + bh; }
    __syncthreads();
    // C2: gates
    if (j < HH) {
      float rg = sigf(gsum[j]);
      float zg = sigf(gsum[HH + j]);
      float ng = tanh_f(gin[j] + rg * ghn[j]);
      hs[j] = (1.0f - zg) * ng + zg * hs[j];
    }
    __syncthreads();
    // C3: projection (pairs), stage, flush every 8 steps
    if (j < 2*CC) {
      int c = j >> 1, half = j & 1;
      float a0 = 0.f, a1 = 0.f;
      #pragma unroll
      for (int qq = 0; qq < 16; ++qq) {
        int q = half*16 + qq;
        float4 hv = *(const float4*)(hs + 4*q);
        float4 wv = ew[q][c];
        a0 = fmaf(wv.x, hv.x, fmaf(wv.y, hv.y, a0));
        a1 = fmaf(wv.z, hv.z, fmaf(wv.w, hv.w, a1));
      }
      float p = a0 + a1;
      p += __shfl_xor(p, 1);
      if (!half) {
        stg[t & 7][c] = eb + p;
        if ((t & 7) == 0) {
          #pragma unroll
          for (int r = 0; r < 8; ++r)
            ctx[((size_t)(t + r)*BB + b)*CC + c] = stg[r][c];  // own writes only
        }
      }
    }
  }
}

// ---------------------------------------------------------------------------
// SDE scan: f-net + g-net + z-update ONLY (h-net evicted to hq_kernel).
// 256 thr/WG (cap 256 VGPR; union of roles ~192 regs -> no spill).
// 3 barriers/step. All global I/O chunked through LDS every 16 steps:
// ctx/noise double-buffered in; z / packed(fd,gd) / zs-out staged and flushed
// into DEAD ctx rows (z_{t} -> row t-1 floats[0:16], fg_t -> row t-1
// floats[16:32] as bf16x2; fg_0 -> row 0 floats[32:48]). ws stays 64MB.
// ---------------------------------------------------------------------------
__global__ __launch_bounds__(256) void sde2_kernel(
    const float* __restrict__ xs, const float* __restrict__ tsv,
    const float* __restrict__ noise,
    const float* __restrict__ fW1, const float* __restrict__ fb1,
    const float* __restrict__ fW2, const float* __restrict__ fb2,
    const float* __restrict__ fW3, const float* __restrict__ fb3,
    const float* __restrict__ gW1, const float* __restrict__ gb1,
    const float* __restrict__ gW2, const float* __restrict__ gb2,
    float* __restrict__ ctxws, float* __restrict__ out)
{
  const int b = blockIdx.x;
  const int j = threadIdx.x;
  const int wid = j >> 6;
  const int lane = j & 63;
  const int dq_d = lane >> 2;
  const int dq_q = lane & 3;
  const int row2 = j >> 1;
  const int hf = j & 1;

  __shared__ __align__(16) float zv[DD];
  __shared__ __align__(16) float x1[HH];
  __shared__ __align__(16) float x2s[HH];
  __shared__ float w3c[HH][17];
  __shared__ float gdpre[DD];
  __shared__ __align__(16) float ctxch[2][16][CC];  // ctx rows chunk
  __shared__ __align__(16) float nch[2][16][DD];    // noise rows chunk
  __shared__ float zst[16][DD];                      // staged z_{i+1}
  __shared__ unsigned fgst[16][DD];                  // staged bf16(fd,gd)

  // wz: fW1 row (j<128) OR g-net slice (j>=128) — shared storage
  float4 wz[20];
  float4 wb[16];
  float bA = 0.f;
  if (j < 128) {
    #pragma unroll
    for (int q = 0; q < 20; ++q) wz[q] = *(const float4*)(fW1 + j*80 + 4*q);
    bA = fb1[j];
  } else {
    int d = (j - 128) >> 3, h0 = ((j - 128) & 7) * 16;
    #pragma unroll
    for (int m = 0; m < 4; ++m) {
      wz[m]     = *(const float4*)(gW1 + d*HH + h0 + 4*m);
      wz[4 + m] = *(const float4*)(gb1 + d*HH + h0 + 4*m);
      wz[8 + m] = *(const float4*)(gW2 + d*HH + h0 + 4*m);
    }
  }
  #pragma unroll
  for (int q = 0; q < 16; ++q) wb[q] = *(const float4*)(fW2 + row2*HH + hf*64 + 4*q);
  const float b2 = fb2[row2];
  float fb3d = 0.f, gb2d = 0.f;
  if (wid == 0) { fb3d = fb3[dq_d]; gb2d = gb2[dq_d]; }

  if (j < HH) {
    #pragma unroll
    for (int d2 = 0; d2 < DD; ++d2) w3c[j][d2] = fW3[d2*HH + j];
  }
  if (j < DD) zv[j] = xs[(size_t)b*DD + j];

  const float dtc = tsv[1] - tsv[0];
  const float sdt = sqrtf(dtc);

  // prolog: chunk 0 (ctx rows 1..16, noise rows 0..15) + zs[0] out
  {
    int r = j >> 4, c4 = j & 15;
    float4 cv = *(const float4*)(ctxws + ((size_t)(1 + r)*BB + b)*CC + c4*4);
    *(float4*)(&ctxch[0][r][c4*4]) = cv;
    if (j < 64) {
      int rn = j >> 2, q4 = j & 3;
      float4 nv = *(const float4*)(noise + ((size_t)rn*BB + b)*DD + q4*4);
      *(float4*)(&nch[0][rn][q4*4]) = nv;
    }
    if (j >= 8 && j < 16) out[2 + (size_t)b*8 + (j - 8)] = xs[(size_t)b*DD + j];
  }
  __syncthreads();

  float4 creg = make_float4(0.f,0.f,0.f,0.f);
  float4 nreg = make_float4(0.f,0.f,0.f,0.f);

  for (int i = 0; i < TT-1; ++i) {
    const int sl = i & 15;
    const int cch = i >> 4;
    const int buf = cch & 1;
    // ---- P0: fL1 -> x1 ; g -> gdpre ; (chunk-start: issue next-chunk loads)
    if (sl == 0 && cch + 1 < 64) {
      int r = j >> 4, c4 = j & 15;
      int rw = 16*(cch + 1) + 1 + r; if (rw > 1023) rw = 1023;
      creg = *(const float4*)(ctxws + ((size_t)rw*BB + b)*CC + c4*4);
      if (j < 64) {
        int rn = 16*(cch + 1) + (j >> 2); if (rn > 1022) rn = 1022;
        nreg = *(const float4*)(noise + ((size_t)rn*BB + b)*DD + (j & 3)*4);
      }
    }
    if (j < 128) {
      float a = dotnq<4>(wz, zv) + dotnq<16>(wz + 4, ctxch[buf][sl]);
      x1[j] = spf(a + bA);
    } else {
      int d = (j - 128) >> 3;
      float zd = zv[d];
      float ps = 0.f;
      #pragma unroll
      for (int m = 0; m < 4; ++m) {
        float4 w1v = wz[m], b1v = wz[4 + m], w2v = wz[8 + m];
        ps += spf(fmaf(zd, w1v.x, b1v.x)) * w2v.x;
        ps += spf(fmaf(zd, w1v.y, b1v.y)) * w2v.y;
        ps += spf(fmaf(zd, w1v.z, b1v.z)) * w2v.z;
        ps += spf(fmaf(zd, w1v.w, b1v.w)) * w2v.w;
      }
      ps += __shfl_xor(ps, 1);
      ps += __shfl_xor(ps, 2);
      ps += __shfl_xor(ps, 4);
      if (((j - 128) & 7) == 0) gdpre[d] = ps;
    }
    __syncthreads();
    // ---- P1: fL2 halves (all threads)
    {
      float p = dotnq<16>(wb, x1 + hf*64);
      p += __shfl_xor(p, 1);
      if (!hf) x2s[row2] = spf(p + b2);
    }
    __syncthreads();
    // ---- P2: fd head + z-update (wave0); chunk flush at chunk end
    if (wid == 0) {
      float fa0 = 0.f, fa1 = 0.f;
      #pragma unroll
      for (int rr = 0; rr < 32; ++rr) {
        int ri = 4*rr + dq_q;
        if (rr & 1) fa1 = fmaf(w3c[ri][dq_d], x2s[ri], fa1);
        else        fa0 = fmaf(w3c[ri][dq_d], x2s[ri], fa0);
      }
      float facc = fa0 + fa1;
      facc += __shfl_xor(facc, 1);
      facc += __shfl_xor(facc, 2);
      if (dq_q == 0) {
        float fd = facc + fb3d;
        float gd = spf(gdpre[dq_d] + gb2d);
        float zpre = zv[dq_d];
        float nw = nch[buf][sl][dq_d];
        float znew = fmaf(fd, dtc, fmaf(gd, sdt * nw, zpre));
        zv[dq_d] = znew;
        zst[sl][dq_d] = znew;
        fgst[sl][dq_d] = bf16pack(fd, gd);
        if (sl == 15 || i == TT-2) {   // flush (reads own lane's writes only)
          int n = sl + 1, base = i - sl, d = dq_d;
          for (int r = 0; r < n; ++r) {
            int si = base + r;
            float zz = zst[r][d];
            ctxws[((size_t)si*BB + b)*CC + d] = zz;               // z_{si+1} overlay
            if (d >= 8)
              out[2 + ((size_t)(si+1)*BB + b)*8 + (d - 8)] = zz;  // zs output
            unsigned fg = fgst[r][d];
            if (si > 0)
              ((unsigned*)ctxws)[((size_t)(si-1)*BB + b)*CC + 16 + d] = fg;
            else
              ((unsigned*)ctxws)[(size_t)b*CC + 32 + d] = fg;
          }
        }
      }
    }
    if (sl == 15 && cch + 1 < 64) {    // commit prefetched chunk to LDS
      int r = j >> 4, c4 = j & 15;
      *(float4*)(&ctxch[buf ^ 1][r][c4*4]) = creg;
      if (j < 64) *(float4*)(&nch[buf ^ 1][j >> 2][(j & 3)*4]) = nreg;
    }
    __syncthreads();
  }
}

// ---------------------------------------------------------------------------
// h-net + logqp: embarrassingly parallel over 1023*256 samples (h-net is NOT
// part of the recurrence). WG=256thr=4 waves, 64 samples/WG; acts in LDS
// transposed [o][s] (bank-clean), weights LDS-transposed so inner-loop W reads
// are wave-uniform b128 broadcasts. One atomicAdd per WG.
// ---------------------------------------------------------------------------
__global__ __launch_bounds__(256) void hq_kernel(
    const float* __restrict__ xs, const float* __restrict__ tsv,
    const float* __restrict__ hW1, const float* __restrict__ hb1,
    const float* __restrict__ hW2, const float* __restrict__ hb2,
    const float* __restrict__ hW3, const float* __restrict__ hb3,
    const float* __restrict__ hW4, const float* __restrict__ hb4,
    const float* __restrict__ ctxws, float* __restrict__ out)
{
  const int w = blockIdx.x;
  const int t = w >> 2;
  const int s = threadIdx.x & 63;
  const int q = threadIdx.x >> 6;
  const int b = (w & 3) * 64 + s;

  __shared__ float act[2][HH][64];
  __shared__ __align__(16) float wT[HH][HH];
  __shared__ float hdL[DD][64];

  float z[16];
  {
    const float* zp = (t == 0) ? (xs + (size_t)b*DD)
                               : (ctxws + ((size_t)(t-1)*BB + b)*CC);
    #pragma unroll
    for (int d4 = 0; d4 < 4; ++d4) {
      float4 v = *(const float4*)(zp + 4*d4);
      z[4*d4] = v.x; z[4*d4+1] = v.y; z[4*d4+2] = v.z; z[4*d4+3] = v.w;
    }
  }
  // stage hW2^T
  for (int e = threadIdx.x; e < HH*HH/4; e += 256) {
    int k = e >> 5, o4 = e & 31;
    float4 v;
    v.x = hW2[(4*o4+0)*HH + k]; v.y = hW2[(4*o4+1)*HH + k];
    v.z = hW2[(4*o4+2)*HH + k]; v.w = hW2[(4*o4+3)*HH + k];
    *(float4*)(&wT[k][o4*4]) = v;
  }
  // layer1 (16 -> 128), thread covers o in [32q, 32q+32)
  #pragma unroll 4
  for (int o1 = 0; o1 < 32; ++o1) {
    int o = 32*q + o1;
    float a = hb1[o];
    #pragma unroll
    for (int k = 0; k < 16; ++k) a = fmaf(z[k], hW1[o*DD + k], a);
    act[0][o][s] = spf(a);
  }
  __syncthreads();
  // layer2 (128 -> 128): act0 -> act1
  {
    float4 ac[8];
    #pragma unroll
    for (int m = 0; m < 8; ++m) ac[m] = *(const float4*)(hb2 + 32*q + 4*m);
    for (int k = 0; k < HH; ++k) {
      float xk = act[0][k][s];
      #pragma unroll
      for (int m = 0; m < 8; ++m) {
        float4 wv = *(const float4*)(&wT[k][32*q + 4*m]);
        ac[m].x = fmaf(xk, wv.x, ac[m].x);
        ac[m].y = fmaf(xk, wv.y, ac[m].y);
        ac[m].z = fmaf(xk, wv.z, ac[m].z);
        ac[m].w = fmaf(xk, wv.w, ac[m].w);
      }
    }
    #pragma unroll
    for (int m = 0; m < 8; ++m) {
      act[1][32*q + 4*m + 0][s] = spf(ac[m].x);
      act[1][32*q + 4*m + 1][s] = spf(ac[m].y);
      act[1][32*q + 4*m + 2][s] = spf(ac[m].z);
      act[1][32*q + 4*m + 3][s] = spf(ac[m].w);
    }
  }
  __syncthreads();
  // restage wT = hW3^T
  for (int e = threadIdx.x; e < HH*HH/4; e += 256) {
    int k = e >> 5, o4 = e & 31;
    float4 v;
    v.x = hW3[(4*o4+0)*HH + k]; v.y = hW3[(4*o4+1)*HH + k];
    v.z = hW3[(4*o4+2)*HH + k]; v.w = hW3[(4*o4+3)*HH + k];
    *(float4*)(&wT[k][o4*4]) = v;
  }
  __syncthreads();
  // layer3: act1 -> act0
  {
    float4 ac[8];
    #pragma unroll
    for (int m = 0; m < 8; ++m) ac[m] = *(const float4*)(hb3 + 32*q + 4*m);
    for (int k = 0; k < HH; ++k) {
      float xk = act[1][k][s];
      #pragma unroll
      for (int m = 0; m < 8; ++m) {
        float4 wv = *(const float4*)(&wT[k][32*q + 4*m]);
        ac[m].x = fmaf(xk, wv.x, ac[m].x);
        ac[m].y = fmaf(xk, wv.y, ac[m].y);
        ac[m].z = fmaf(xk, wv.z, ac[m].z);
        ac[m].w = fmaf(xk, wv.w, ac[m].w);
      }
    }
    #pragma unroll
    for (int m = 0; m < 8; ++m) {
      act[0][32*q + 4*m + 0][s] = spf(ac[m].x);
      act[0][32*q + 4*m + 1][s] = spf(ac[m].y);
      act[0][32*q + 4*m + 2][s] = spf(ac[m].z);
      act[0][32*q + 4*m + 3][s] = spf(ac[m].w);
    }
  }
  __syncthreads();
  // restage wT[:, 0:16] = hW4^T
  for (int e = threadIdx.x; e < HH*4; e += 256) {
    int k = e >> 2, o4 = e & 3;
    float4 v;
    v.x = hW4[(4*o4+0)*HH + k]; v.y = hW4[(4*o4+1)*HH + k];
    v.z = hW4[(4*o4+2)*HH + k]; v.w = hW4[(4*o4+3)*HH + k];
    *(float4*)(&wT[k][o4*4]) = v;
  }
  __syncthreads();
  // layer4 (128 -> 16), wave q computes o in [4q, 4q+4)
  {
    float4 a4 = *(const float4*)(hb4 + 4*q);
    for (int k = 0; k < HH; ++k) {
      float xk = act[0][k][s];
      float4 wv = *(const float4*)(&wT[k][4*q]);
      a4.x = fmaf(xk, wv.x, a4.x);
      a4.y = fmaf(xk, wv.y, a4.y);
      a4.z = fmaf(xk, wv.z, a4.z);
      a4.w = fmaf(xk, wv.w, a4.w);
    }
    hdL[4*q + 0][s] = a4.x; hdL[4*q + 1][s] = a4.y;
    hdL[4*q + 2][s] = a4.z; hdL[4*q + 3][s] = a4.w;
  }
  __syncthreads();
  // u, dlq, reduce
  if (q == 0) {
    const float dtc = tsv[1] - tsv[0];
    const unsigned* fgp = (const unsigned*)ctxws;
    size_t base = (t > 0) ? (((size_t)(t-1)*BB + b)*CC + 16)
                          : ((size_t)b*CC + 32);
    float acc = 0.f;
    #pragma unroll
    for (int d = 0; d < 16; ++d) {
      unsigned fg = fgp[base + d];
      float fd = __uint_as_float(fg << 16);
      float gd = __uint_as_float(fg & 0xFFFF0000u);
      float u = (fd - hdL[d][s]) * rcp_f(gd + 1e-7f);
      acc = fmaf(u, u, acc);
    }
    acc *= 0.5f * dtc;
    #pragma unroll
    for (int m = 1; m < 64; m <<= 1) acc += __shfl_xor(acc, m);
    if (s == 0) atomicAdd(out + 1, acc * (1.0f / 256.0f));
  }
}

// ---------------------------------------------------------------------------
// log_pxs reduction
// ---------------------------------------------------------------------------
__global__ __launch_bounds__(256) void lp_kernel(const float* __restrict__ xs,
                                                 float* __restrict__ out)
{
  const int t = blockIdx.x;
  const int b = threadIdx.x;
  const float cst = 3.6862316527834183f;  // -log(0.01) - 0.5*log(2*pi)
  const float* xrow = xs + ((size_t)t*BB + b)*DD + 8;
  const float* zrow = out + 2 + ((size_t)t*BB + b)*8;
  float acc = 0.f;
  #pragma unroll
  for (int o = 0; o < 8; ++o) {
    float dd = (xrow[o] - zrow[o]) * 100.0f;
    acc += cst - 0.5f * dd * dd;
  }
  #pragma unroll
  for (int m = 1; m < 64; m <<= 1) acc += __shfl_xor(acc, m);
  __shared__ float wpart[4];
  int w = threadIdx.x >> 6;
  if ((threadIdx.x & 63) == 0) wpart[w] = acc;
  __syncthreads();
  if (threadIdx.x == 0)
    atomicAdd(out, (wpart[0] + wpart[1] + wpart[2] + wpart[3]) * (1.0f / 256.0f));
}

extern "C" void kernel_launch(void* const* d_in, const int* in_sizes, int n_in,
                              void* d_out, int out_size, void* d_ws, size_t ws_size,
                              hipStream_t stream) {
  const float* xs    = (const float*)d_in[0];
  const float* tsv   = (const float*)d_in[1];
  const float* noise = (const float*)d_in[2];
  const float* Wih   = (const float*)d_in[3];
  const float* Whh   = (const float*)d_in[4];
  const float* bih   = (const float*)d_in[5];
  const float* bhh   = (const float*)d_in[6];
  const float* encW  = (const float*)d_in[7];
  const float* encB  = (const float*)d_in[8];
  const float* fW1   = (const float*)d_in[9];
  const float* fb1   = (const float*)d_in[10];
  const float* fW2   = (const float*)d_in[11];
  const float* fb2   = (const float*)d_in[12];
  const float* fW3   = (const float*)d_in[13];
  const float* fb3   = (const float*)d_in[14];
  const float* hW1   = (const float*)d_in[15];
  const float* hb1   = (const float*)d_in[16];
  const float* hW2   = (const float*)d_in[17];
  const float* hb2   = (const float*)d_in[18];
  const float* hW3   = (const float*)d_in[19];
  const float* hb3   = (const float*)d_in[20];
  const float* hW4   = (const float*)d_in[21];
  const float* hb4   = (const float*)d_in[22];
  const float* gW1   = (const float*)d_in[23];
  const float* gb1   = (const float*)d_in[24];
  const float* gW2   = (const float*)d_in[25];
  const float* gb2   = (const float*)d_in[26];
  float* out = (float*)d_out;
  float* ctxws = (float*)d_ws;   // 64 MiB: ctx + (z,fd,gd) overlay in dead rows

  hipMemsetAsync(d_out, 0, 2 * sizeof(float), stream);
  enc_kernel<<<BB, 384, 0, stream>>>(xs, Wih, Whh, bih, bhh, encW, encB, ctxws);
  sde2_kernel<<<BB, 256, 0, stream>>>(xs, tsv, noise,
                                      fW1, fb1, fW2, fb2, fW3, fb3,
                                      gW1, gb1, gW2, gb2, ctxws, out);
  hq_kernel<<<(TT-1)*4, 256, 0, stream>>>(xs, tsv,
                                          hW1, hb1, hW2, hb2, hW3, hb3, hW4, hb4,
                                          ctxws, out);
  lp_kernel<<<TT, BB, 0, stream>>>(xs, out);
}